// Round 7
// baseline (1206.254 us; speedup 1.0000x reference)
//
#include <hip/hip_runtime.h>
#include <hip/hip_bf16.h>
#include <math.h>

// Problem constants: B(=T)=8, C=256, H=W=64, N=4096, heads=8, d=32.
#define T_ 8
#define C_ 256
#define N_ 4096          // H*W
#define CN_ (C_ * N_)    // 1048576 elements per timestep
#define EPSB 1e-5f
#define NBLK 512         // persistent grid: 512 blocks = 2/CU exactly

typedef unsigned long long u64;
typedef unsigned int u32;
typedef short bf16x8 __attribute__((ext_vector_type(8)));
typedef short bf16x4 __attribute__((ext_vector_type(4)));
typedef float f32x4 __attribute__((ext_vector_type(4)));

static __device__ __forceinline__ unsigned short f2bf(float f) {
    __hip_bfloat16 h = __float2bfloat16(f);   // RTNE
    return *(unsigned short*)&h;
}
static __device__ __forceinline__ float bf2f(unsigned short u) {
    u32 x = (u32)u << 16;                     // exact widen
    return *(float*)&x;
}

typedef const __attribute__((address_space(1))) unsigned int ga_u32;
typedef __attribute__((address_space(3))) unsigned int la_u32;
static __device__ __forceinline__ void gl_lds16(const unsigned short* g,
                                                unsigned short* l_) {
    __builtin_amdgcn_global_load_lds((ga_u32*)g, (la_u32*)l_, 16, 0, 0);
}

#define DRAIN_BAR() asm volatile("s_waitcnt vmcnt(0)\ns_barrier" ::: "memory")

// ---------------------------------------------------------------------------
// 80 KiB LDS union shared by all phases (exactly 2 blocks/CU at 160 KiB).
union SharedU {
    struct { unsigned short As[2][24][512]; unsigned short Bs[2][8][512]; } s;       // 64K
    struct { unsigned short As[2][24][512]; unsigned short Bh[2][8][512];
             unsigned short Bl[2][8][512]; } f;                                      // 80K
    struct { float L[8][10][68]; float invs[8], bs[8], ms[8], pads[8]; } dw;         // ~22K
    struct { u64 ks[8][65]; u64 vs[32][65]; } kv;                                    // ~21K
    float kvs[1024];                                                                 // 4K
};

// ---------------------------------------------------------------------------
// Device-wide sense-reversing barrier. bar[0]=count, bar[1]=generation,
// zeroed by hipMemsetAsync before launch. __threadfence() = agent-scope
// fence (L2 writeback+invalidate on gfx950) -> cross-XCD visibility.
static __device__ __forceinline__ void grid_barrier(unsigned* bar) {
    __syncthreads();
    if (threadIdx.x == 0) {
        __threadfence();                                   // release block's writes
        unsigned g = __hip_atomic_load(&bar[1], __ATOMIC_RELAXED, __HIP_MEMORY_SCOPE_AGENT);
        unsigned a = __hip_atomic_fetch_add(&bar[0], 1u, __ATOMIC_ACQ_REL, __HIP_MEMORY_SCOPE_AGENT);
        if (a == NBLK - 1u) {
            __hip_atomic_store(&bar[0], 0u, __ATOMIC_RELAXED, __HIP_MEMORY_SCOPE_AGENT);
            __hip_atomic_fetch_add(&bar[1], 1u, __ATOMIC_RELEASE, __HIP_MEMORY_SCOPE_AGENT);
        } else {
            while (__hip_atomic_load(&bar[1], __ATOMIC_RELAXED, __HIP_MEMORY_SCOPE_AGENT) == g)
                __builtin_amdgcn_s_sleep(2);
        }
        __threadfence();                                   // acquire others' writes
    }
    __syncthreads();
}

// ---------------------------------------------------------------------------
// Phase bodies — verbatim arithmetic from the R6 kernels.

// LIF(x) + fragment layout (transposed ownership, no LDS).
static __device__ __forceinline__ void lifx_body(const float* __restrict__ X,
                                                 unsigned short* __restrict__ ST,
                                                 int bx, int by, int tid) {
    int n = bx * 256 + tid;
    int c0 = by * 8;
    int k32 = c0 >> 5, quad = (c0 >> 3) & 3;
    size_t base = (size_t)c0 * N_ + n;
    size_t pos = ((size_t)((n >> 4) * 8 + k32)) * 512 +
                 (size_t)((quad * 16 + (n & 15)) * 8);
    float v[8];
#pragma unroll
    for (int j = 0; j < 8; j++) v[j] = 0.f;
#pragma unroll
    for (int t = 0; t < T_; t++) {
        bf16x8 bs;
#pragma unroll
        for (int j = 0; j < 8; j++) {
            float xt = X[(size_t)t * CN_ + base + (size_t)j * N_];
            float vv = v[j] + (xt - v[j]) / 2.0f;
            int s = (vv - 1.0f >= 0.f) ? 1 : 0;
            bs[j] = s ? (short)0x3F80 : (short)0;
            v[j] = s ? 0.f : vv;
        }
        *(bf16x8*)&ST[(size_t)t * CN_ + pos] = bs;
    }
}

// Exact 3-way bf16 split of one weight element.
static __device__ __forceinline__ void splitw_body(const float* __restrict__ w,
                                                   unsigned short* __restrict__ out,
                                                   int mat, int idx) {
    int m = idx >> 8, k = idx & 255;
    float wv = w[idx];
    unsigned short h1 = f2bf(wv);
    float f1 = bf2f(h1);
    unsigned short h2 = f2bf(wv - f1);
    unsigned short h3 = f2bf(wv - f1 - bf2f(h2));
    int lane = ((k >> 3) & 3) * 16 + (m & 15);
    size_t pos = ((size_t)(((m >> 4) * 8 + (k >> 5)) * 64 + lane)) * 8 + (k & 7);
    size_t base = (size_t)mat * 3 * 65536;
    out[base + pos] = h1;
    out[base + 65536 + pos] = h2;
    out[base + 2 * 65536 + pos] = h3;
}

// Fused dw+BN+pad+split (8 output rows/block). Trailing sync for LDS reuse.
static __device__ __forceinline__ void dw_body(const float* __restrict__ Yt,
                                               const float* __restrict__ dw,
                                               const float* __restrict__ bnp,
                                               unsigned short* __restrict__ Bh,
                                               unsigned short* __restrict__ Bl,
                                               int y0, int cg, int tid, SharedU* sh) {
    int c0 = cg * 8;
    float (*L)[10][68] = sh->dw.L;
    float* invs = sh->dw.invs;
    float* bs_ = sh->dw.bs;
    float* ms_ = sh->dw.ms;
    float* pads_ = sh->dw.pads;

    if (tid < 8) {
        int c = c0 + tid;
        float w = bnp[c], b = bnp[256 + c], m = bnp[512 + c], var = bnp[768 + c];
        float sq = sqrtf(var + EPSB);
        invs[tid] = w / sq;
        bs_[tid] = b;
        ms_[tid] = m;
        pads_[tid] = b - (m * w) / sq;
    }
    __syncthreads();

    for (int i = tid; i < 8 * 10 * 66; i += 256) {
        int c = i / 660;
        int rem = i - c * 660;
        int row = rem / 66, col = rem - row * 66;
        int gy = y0 - 1 + row, gx = col - 1;
        float val;
        if (gy < 0 || gy > 63 || gx < 0 || gx > 63) val = pads_[c];
        else val = (Yt[(size_t)(c0 + c) * N_ + gy * 64 + gx] - ms_[c]) * invs[c] + bs_[c];
        L[c][row][col] = val;
    }
    __syncthreads();

    int x = tid & 63, ry = tid >> 6;
#pragma unroll
    for (int h = 0; h < 2; h++) {
        int r = ry + 4 * h;
        int n = (y0 + r) * 64 + x;
        bf16x8 hi, lo;
#pragma unroll
        for (int j = 0; j < 8; j++) {
            const float* dwc = dw + (c0 + j) * 9;
            float a = 0.f;
#pragma unroll
            for (int dy = 0; dy < 3; dy++)
#pragma unroll
                for (int dx = 0; dx < 3; dx++)
                    a += dwc[dy * 3 + dx] * L[j][r + dy][x + dx];
            unsigned short hh = f2bf(a);
            hi[j] = (short)hh;
            lo[j] = (short)f2bf(a - bf2f(hh));
        }
        size_t pos = ((size_t)((n >> 4) * 8 + (cg >> 2))) * 512 +
                     (size_t)(((cg & 3) * 16 + (n & 15)) * 8);
        *(bf16x8*)&Bh[pos] = hi;
        *(bf16x8*)&Bl[pos] = lo;
    }
    __syncthreads();   // LDS reuse across virtual tiles
}

// R3-verified 2-phase GEMM cores (907 TF), LDS passed in.
static __device__ __forceinline__ void gemm_s_core(const unsigned short* __restrict__ Wsp,
                                                   const unsigned short* __restrict__ Bt,
                                                   float* __restrict__ Yt,
                                                   int bx, int by, int tid,
                                                   unsigned short (*As)[24][512],
                                                   unsigned short (*Bs)[8][512]) {
    int l = tid & 63, wave = tid >> 6;
    int wm = wave >> 1, wn = wave & 1;
    int lcol = l & 15, quad = l >> 4;

    f32x4 acc[4][4];
#pragma unroll
    for (int i = 0; i < 4; i++)
#pragma unroll
        for (int j = 0; j < 4; j++) acc[i][j] = (f32x4){0.f, 0.f, 0.f, 0.f};

    const unsigned short* src[8];
    unsigned short* d0[8];
    unsigned short* d1[8];
#pragma unroll
    for (int i = 0; i < 8; i++) {
        int tau = wave * 8 + i;
        if (tau < 24) {
            int s = tau >> 3, mtg = tau & 7;
            src[i] = &Wsp[(size_t)s * 65536 + ((size_t)((by * 8 + mtg) * 8)) * 512 + l * 8];
            d0[i] = &As[0][tau][0];
            d1[i] = &As[1][tau][0];
        } else {
            int nt = tau - 24;
            src[i] = &Bt[((size_t)((bx * 8 + nt) * 8)) * 512 + l * 8];
            d0[i] = &Bs[0][nt][0];
            d1[i] = &Bs[1][nt][0];
        }
    }

    auto stg0 = [&]() {
#pragma unroll
        for (int i = 0; i < 8; i++) { gl_lds16(src[i], d0[i]); src[i] += 512; }
    };
    auto stg1 = [&]() {
#pragma unroll
        for (int i = 0; i < 8; i++) { gl_lds16(src[i], d1[i]); src[i] += 512; }
    };
    auto compute = [&](const unsigned short (*Asp)[512],
                       const unsigned short (*Bsp)[512]) {
        bf16x8 bfr[4];
#pragma unroll
        for (int nt = 0; nt < 4; nt++)
            bfr[nt] = *(const bf16x8*)&Bsp[wn * 4 + nt][l * 8];
#pragma unroll
        for (int s = 0; s < 3; s++)
#pragma unroll
            for (int mt = 0; mt < 4; mt++) {
                bf16x8 afr = *(const bf16x8*)&Asp[s * 8 + wm * 4 + mt][l * 8];
#pragma unroll
                for (int nt = 0; nt < 4; nt++)
                    acc[mt][nt] = __builtin_amdgcn_mfma_f32_16x16x32_bf16(
                        afr, bfr[nt], acc[mt][nt], 0, 0, 0);
            }
    };

    stg0();
    DRAIN_BAR();
    for (int kk = 0; kk < 8; kk += 2) {
        stg1();
        compute(As[0], Bs[0]);
        DRAIN_BAR();
        if (kk < 6) stg0();
        compute(As[1], Bs[1]);
        DRAIN_BAR();
    }

    int m0 = by * 128, n0 = bx * 128;
#pragma unroll
    for (int mt = 0; mt < 4; mt++)
#pragma unroll
        for (int i = 0; i < 4; i++) {
            int row = m0 + wm * 64 + mt * 16 + quad * 4 + i;
            float* yr = &Yt[(size_t)row * N_ + n0 + wn * 64 + lcol];
#pragma unroll
            for (int nt = 0; nt < 4; nt++) yr[nt * 16] = acc[mt][nt][i];
        }
}

static __device__ __forceinline__ void gemm_f_core(const unsigned short* __restrict__ Wsp,
                                                   const unsigned short* __restrict__ Bht,
                                                   const unsigned short* __restrict__ Blt,
                                                   float* __restrict__ Yt,
                                                   const float* __restrict__ bnp,
                                                   int bx, int by, int tid,
                                                   unsigned short (*As)[24][512],
                                                   unsigned short (*Bhs)[8][512],
                                                   unsigned short (*Bls)[8][512]) {
    int l = tid & 63, wave = tid >> 6;
    int wm = wave >> 1, wn = wave & 1;
    int lcol = l & 15, quad = l >> 4;

    f32x4 acc[4][4];
#pragma unroll
    for (int i = 0; i < 4; i++)
#pragma unroll
        for (int j = 0; j < 4; j++) acc[i][j] = (f32x4){0.f, 0.f, 0.f, 0.f};

    const unsigned short* src[10];
    unsigned short* d0[10];
    unsigned short* d1[10];
#pragma unroll
    for (int i = 0; i < 10; i++) {
        int tau = wave * 10 + i;
        if (tau < 24) {
            int s = tau >> 3, mtg = tau & 7;
            src[i] = &Wsp[(size_t)s * 65536 + ((size_t)((by * 8 + mtg) * 8)) * 512 + l * 8];
            d0[i] = &As[0][tau][0];
            d1[i] = &As[1][tau][0];
        } else if (tau < 32) {
            int nt = tau - 24;
            src[i] = &Bht[((size_t)((bx * 8 + nt) * 8)) * 512 + l * 8];
            d0[i] = &Bhs[0][nt][0];
            d1[i] = &Bhs[1][nt][0];
        } else {
            int nt = tau - 32;
            src[i] = &Blt[((size_t)((bx * 8 + nt) * 8)) * 512 + l * 8];
            d0[i] = &Bls[0][nt][0];
            d1[i] = &Bls[1][nt][0];
        }
    }

    auto stg0 = [&]() {
#pragma unroll
        for (int i = 0; i < 10; i++) { gl_lds16(src[i], d0[i]); src[i] += 512; }
    };
    auto stg1 = [&]() {
#pragma unroll
        for (int i = 0; i < 10; i++) { gl_lds16(src[i], d1[i]); src[i] += 512; }
    };
    auto compute = [&](const unsigned short (*Asp)[512],
                       const unsigned short (*Bhp)[512],
                       const unsigned short (*Blp)[512]) {
        bf16x8 bh[4], bl[4];
#pragma unroll
        for (int nt = 0; nt < 4; nt++) {
            bh[nt] = *(const bf16x8*)&Bhp[wn * 4 + nt][l * 8];
            bl[nt] = *(const bf16x8*)&Blp[wn * 4 + nt][l * 8];
        }
#pragma unroll
        for (int s = 0; s < 3; s++)
#pragma unroll
            for (int mt = 0; mt < 4; mt++) {
                bf16x8 afr = *(const bf16x8*)&Asp[s * 8 + wm * 4 + mt][l * 8];
#pragma unroll
                for (int nt = 0; nt < 4; nt++)
                    acc[mt][nt] = __builtin_amdgcn_mfma_f32_16x16x32_bf16(
                        afr, bh[nt], acc[mt][nt], 0, 0, 0);
                if (s < 2) {
#pragma unroll
                    for (int nt = 0; nt < 4; nt++)
                        acc[mt][nt] = __builtin_amdgcn_mfma_f32_16x16x32_bf16(
                            afr, bl[nt], acc[mt][nt], 0, 0, 0);
                }
            }
    };

    stg0();
    DRAIN_BAR();
    for (int kk = 0; kk < 8; kk += 2) {
        stg1();
        compute(As[0], Bhs[0], Bls[0]);
        DRAIN_BAR();
        if (kk < 6) stg0();
        compute(As[1], Bhs[1], Bls[1]);
        DRAIN_BAR();
    }

    int m0 = by * 128, n0 = bx * 128;
#pragma unroll
    for (int mt = 0; mt < 4; mt++)
#pragma unroll
        for (int i = 0; i < 4; i++) {
            int row = m0 + wm * 64 + mt * 16 + quad * 4 + i;
            float i1 = bnp[1024 + row] / sqrtf(bnp[1024 + 768 + row] + EPSB);
            float b1 = bnp[1024 + 256 + row], m1 = bnp[1024 + 512 + row];
            float i2 = bnp[2048 + row] / sqrtf(bnp[2048 + 768 + row] + EPSB);
            float b2 = bnp[2048 + 256 + row], m2 = bnp[2048 + 512 + row];
            float* yr = &Yt[(size_t)row * N_ + n0 + wn * 64 + lcol];
#pragma unroll
            for (int nt = 0; nt < 4; nt++)
                yr[nt * 16] = ((acc[mt][nt][i] - m1) * i1 + b1 - m2) * i2 + b2;
        }
}

// Branch-indexed LIF: br 0 -> u8 spikes (q), br 1/2 -> bitpacked (k, v).
static __device__ __forceinline__ void lif3_body(const float* __restrict__ X,
                                                 unsigned char* sq, u64* kbp, u64* vbp,
                                                 int br, int idx, int tid) {
    int lane = tid & 63;
    u64* BP = (br == 1) ? kbp : vbp;
    float v = 0.f;
#pragma unroll
    for (int t = 0; t < T_; t++) {
        float xt = X[(size_t)t * CN_ + idx];
        v = v + (xt - v) / 2.0f;
        int s = (v - 1.0f >= 0.f) ? 1 : 0;
        if (br == 0) {
            sq[(size_t)t * CN_ + idx] = (unsigned char)s;
        } else {
            u64 mask = __ballot(s);
            if (lane == 0) BP[((size_t)t * CN_ + idx) >> 6] = mask;
        }
        if (s) v = 0.f;
    }
}

// Bitpacked kv quadrant (256 threads, exact integer popcounts).
static __device__ __forceinline__ void kv_body(const u64* __restrict__ kb,
                                               const u64* __restrict__ vb_,
                                               float* __restrict__ kvout,
                                               int q, int tid, SharedU* sh) {
    u64 (*ks)[65] = sh->kv.ks;
    u64 (*vs)[65] = sh->kv.vs;
    for (int i = tid; i < 512; i += 256) {        // 8 ks rows (d = q*8 + r)
        int r = i >> 6, w = i & 63;
        ks[r][w] = kb[(q * 8 + r) * 64 + w];
    }
    for (int i = tid; i < 2048; i += 256) {       // all 32 vs rows
        int r = i >> 6, w = i & 63;
        vs[r][w] = vb_[r * 64 + w];
    }
    __syncthreads();
    int dq = tid >> 5, e = tid & 31;
    int cnt = 0;
#pragma unroll
    for (int w = 0; w < 64; w++)
        cnt += __popcll(ks[dq][w] & vs[e][w]);
    kvout[(q * 8 + dq) * 32 + e] = (float)cnt;
    __syncthreads();
}

// o = scale*q.kv + LIF(o) + fragment store (R6 v2 partition).
static __device__ __forceinline__ void olif_body(const unsigned char* __restrict__ q,
                                                 const float* __restrict__ kvbuf,
                                                 unsigned short* __restrict__ ST,
                                                 int bx, int h, int tid, SharedU* sh) {
    float* kvs = sh->kvs;
    int nb = bx * 32;
    int nj = tid & 31, g = tid >> 5;
    int n = nb + nj;
    int e0 = g * 4;
    const float scale = 0.17677669529663687f;
    float v[4];
#pragma unroll
    for (int e = 0; e < 4; e++) v[e] = 0.f;
    size_t pos = ((size_t)((n >> 4) * 8 + h)) * 512 +
                 (size_t)(((g >> 1) * 16 + (n & 15)) * 8) + (size_t)(4 * (g & 1));
#pragma unroll
    for (int t = 0; t < T_; t++) {
        for (int i = tid; i < 1024; i += 256)
            kvs[i] = kvbuf[(size_t)(t * 8 + h) * 1024 + i];
        __syncthreads();
        float acc[4];
#pragma unroll
        for (int e = 0; e < 4; e++) acc[e] = 0.f;
        const unsigned char* qb = q + (size_t)t * CN_ + (size_t)(h * 32) * N_ + n;
#pragma unroll 4
        for (int d = 0; d < 32; d++) {
            float qd = (float)qb[(size_t)d * N_];
#pragma unroll
            for (int e = 0; e < 4; e++)
                acc[e] += qd * kvs[d * 32 + e0 + e];
        }
        bf16x4 w;
#pragma unroll
        for (int e = 0; e < 4; e++) {
            float o = acc[e] * scale;
            v[e] = v[e] + (o - v[e]) / 2.0f;
            int s = (v[e] - 1.0f >= 0.f) ? 1 : 0;
            w[e] = s ? (short)0x3F80 : (short)0;
            if (s) v[e] = 0.f;
        }
        *(bf16x4*)&ST[(size_t)t * CN_ + pos] = w;
        __syncthreads();
    }
}

// ---------------------------------------------------------------------------
struct MegaArgs {
    const float* x;
    const float* w8[8];          // q_w1,q_pw,k_w1,k_pw,v_w1,v_pw,p_w1,p_pw
    const float* dwp[3];         // q_dw,k_dw,v_dw
    const float* bnp[3];         // q_bn,k_bn,v_bn
    const float* p_dw;
    const float* p_bn;
    unsigned short* wspA;
    unsigned short* ST;
    float* F[3];
    unsigned short* Ph[3];
    unsigned short* Pl[3];
    unsigned char* sq;
    u64* kbp;
    u64* vbp;
    float* kvbuf;
    float* out;
    unsigned short* Pph;
    unsigned short* Ppl;
    unsigned* bar;
};

__global__ __launch_bounds__(256, 2) void mega(MegaArgs a) {
    __shared__ SharedU sh;
    int bid = blockIdx.x, tid = threadIdx.x;
    const size_t WS3 = 3 * 65536;

    // P0: split_w (2048 vt) + lif_x_frag (512 vt)
    for (int vb = bid; vb < 2560; vb += NBLK) {
        if (vb < 2048) splitw_body(a.w8[vb >> 8], a.wspA, vb >> 8, (vb & 255) * 256 + tid);
        else { int u = vb - 2048; lifx_body(a.x, a.ST, u & 15, u >> 4, tid); }
    }
    grid_barrier(a.bar);

    // P1: gemm_s3 (1536 vt, old order: linear = t*192 + y*32 + bx)
    for (int r = 0; r < 3; r++) {
        int vb = bid + r * NBLK;
        int bx = vb & 31, rest = vb >> 5;
        int y = rest % 6, t = rest / 6;
        int br = y >> 1, byl = y & 1;
        gemm_s_core(a.wspA + (size_t)(br * 2) * WS3, a.ST + (size_t)t * CN_,
                    a.F[br] + (size_t)t * CN_, bx, byl, tid, sh.s.As, sh.s.Bs);
    }
    grid_barrier(a.bar);

    // P2: dw3 (6144 vt)
    for (int r = 0; r < 12; r++) {
        int vb = bid + r * NBLK;
        int x8 = vb & 7, y = (vb >> 3) & 31, z = vb >> 8;
        int br = z >> 3, t = z & 7;
        dw_body(a.F[br] + (size_t)t * CN_, a.dwp[br], a.bnp[br],
                a.Ph[br] + (size_t)t * CN_, a.Pl[br] + (size_t)t * CN_,
                x8 * 8, y, tid, &sh);
    }
    grid_barrier(a.bar);

    // P3: gemm_f3 (1536 vt)
    for (int r = 0; r < 3; r++) {
        int vb = bid + r * NBLK;
        int bx = vb & 31, rest = vb >> 5;
        int y = rest % 6, t = rest / 6;
        int br = y >> 1, byl = y & 1;
        gemm_f_core(a.wspA + (size_t)(br * 2 + 1) * WS3,
                    a.Ph[br] + (size_t)t * CN_, a.Pl[br] + (size_t)t * CN_,
                    a.F[br] + (size_t)t * CN_, a.bnp[br], bx, byl, tid,
                    sh.f.As, sh.f.Bh, sh.f.Bl);
    }
    grid_barrier(a.bar);

    // P4: lif3 (12288 vt)
    for (int r = 0; r < 24; r++) {
        int vb = bid + r * NBLK;
        int blk = vb & 4095, br = vb >> 12;
        lif3_body(a.F[br], a.sq, a.kbp, a.vbp, br, blk * 256 + tid, tid);
    }
    grid_barrier(a.bar);

    // P5: attn_kv (256 vt: (t,h) x 4 d-quadrants); blocks >= 256 idle
    if (bid < 256) {
        int th = bid >> 2, q = bid & 3;
        int t = th >> 3, h = th & 7;
        kv_body(a.kbp + ((size_t)t * C_ + h * 32) * 64,
                a.vbp + ((size_t)t * C_ + h * 32) * 64,
                a.kvbuf + (size_t)th * 1024, q, tid, &sh);
    }
    grid_barrier(a.bar);

    // P6: attn_olif (1024 vt)
    for (int r = 0; r < 2; r++) {
        int vb = bid + r * NBLK;
        olif_body(a.sq, a.kvbuf, a.ST, vb & 127, vb >> 7, tid, &sh);
    }
    grid_barrier(a.bar);

    // P7: gemm_s2 (512 vt)
    {
        int bx = bid & 31, by = (bid >> 5) & 1, t = bid >> 6;
        gemm_s_core(a.wspA + 6 * WS3, a.ST + (size_t)t * CN_,
                    a.out + (size_t)t * CN_, bx, by, tid, sh.s.As, sh.s.Bs);
    }
    grid_barrier(a.bar);

    // P8: dw_bn_split p (2048 vt)
    for (int r = 0; r < 4; r++) {
        int vb = bid + r * NBLK;
        int x8 = vb & 7, y = (vb >> 3) & 31, t = vb >> 8;
        dw_body(a.out + (size_t)t * CN_, a.p_dw, a.p_bn,
                a.Pph + (size_t)t * CN_, a.Ppl + (size_t)t * CN_,
                x8 * 8, y, tid, &sh);
    }
    grid_barrier(a.bar);

    // P9: gemm_f2 (512 vt)
    {
        int bx = bid & 31, by = (bid >> 5) & 1, t = bid >> 6;
        gemm_f_core(a.wspA + 7 * WS3, a.Pph + (size_t)t * CN_, a.Ppl + (size_t)t * CN_,
                    a.out + (size_t)t * CN_, a.p_bn, bx, by, tid,
                    sh.f.As, sh.f.Bh, sh.f.Bl);
    }
}

// ---------------------------------------------------------------------------
extern "C" void kernel_launch(void* const* d_in, const int* in_sizes, int n_in,
                              void* d_out, int out_size, void* d_ws, size_t ws_size,
                              hipStream_t stream) {
    const float* x = (const float*)d_in[0];
    const float* q_w1 = (const float*)d_in[1];
    const float* q_dw = (const float*)d_in[2];
    const float* q_pw = (const float*)d_in[3];
    const float* q_bn = (const float*)d_in[4];
    const float* k_w1 = (const float*)d_in[5];
    const float* k_dw = (const float*)d_in[6];
    const float* k_pw = (const float*)d_in[7];
    const float* k_bn = (const float*)d_in[8];
    const float* v_w1 = (const float*)d_in[9];
    const float* v_dw = (const float*)d_in[10];
    const float* v_pw = (const float*)d_in[11];
    const float* v_bn = (const float*)d_in[12];
    const float* p_w1 = (const float*)d_in[13];
    const float* p_dw = (const float*)d_in[14];
    const float* p_pw = (const float*)d_in[15];
    const float* p_bn = (const float*)d_in[16];

    const size_t SZ = (size_t)T_ * CN_;   // 8,388,608 elements
    float* out = (float*)d_out;
    float* F0 = (float*)d_ws;
    float* F1 = F0 + SZ;
    float* F2 = F1 + SZ;
    float* P0 = F2 + SZ;
    float* P1 = P0 + SZ;
    float* P2 = P1 + SZ;
    float* bufKV = P2 + SZ;               // 65,536 floats
    unsigned char* xs = (unsigned char*)(bufKV + 65536);   // spare: barrier lives here
    unsigned char* sq = xs + SZ;
    u64* kbp = (u64*)(sq + SZ);
    u64* vbp = kbp + (SZ >> 6);
    unsigned short* wspA = (unsigned short*)(vbp + (SZ >> 6));
    unsigned short* ST = wspA + 8 * 3 * 65536;

    unsigned short* P0h = (unsigned short*)P0; unsigned short* P0l = P0h + SZ;
    unsigned short* P1h = (unsigned short*)P1; unsigned short* P1l = P1h + SZ;
    unsigned short* P2h = (unsigned short*)P2; unsigned short* P2l = P2h + SZ;

    unsigned* bar = (unsigned*)xs;        // [count, generation]
    hipMemsetAsync(bar, 0, 16, stream);

    MegaArgs ma;
    ma.x = x;
    ma.w8[0] = q_w1; ma.w8[1] = q_pw; ma.w8[2] = k_w1; ma.w8[3] = k_pw;
    ma.w8[4] = v_w1; ma.w8[5] = v_pw; ma.w8[6] = p_w1; ma.w8[7] = p_pw;
    ma.dwp[0] = q_dw; ma.dwp[1] = k_dw; ma.dwp[2] = v_dw;
    ma.bnp[0] = q_bn; ma.bnp[1] = k_bn; ma.bnp[2] = v_bn;
    ma.p_dw = p_dw; ma.p_bn = p_bn;
    ma.wspA = wspA; ma.ST = ST;
    ma.F[0] = F0; ma.F[1] = F1; ma.F[2] = F2;
    ma.Ph[0] = P0h; ma.Ph[1] = P1h; ma.Ph[2] = P2h;
    ma.Pl[0] = P0l; ma.Pl[1] = P1l; ma.Pl[2] = P2l;
    ma.sq = sq; ma.kbp = kbp; ma.vbp = vbp; ma.kvbuf = bufKV;
    ma.out = out;
    ma.Pph = P0h; ma.Ppl = P0l;
    ma.bar = bar;

    mega<<<dim3(NBLK), dim3(256), 0, stream>>>(ma);
}

// Round 8
// 412.612 us; speedup vs baseline: 2.9235x; 2.9235x over previous
//
#include <hip/hip_runtime.h>
#include <hip/hip_bf16.h>
#include <math.h>

// Problem constants: B(=T)=8, C=256, H=W=64, N=4096, heads=8, d=32.
#define T_ 8
#define C_ 256
#define N_ 4096          // H*W
#define CN_ (C_ * N_)    // 1048576 elements per timestep
#define EPSB 1e-5f

typedef unsigned long long u64;
typedef unsigned int u32;
typedef short bf16x8 __attribute__((ext_vector_type(8)));
typedef short bf16x4 __attribute__((ext_vector_type(4)));
typedef float f32x4 __attribute__((ext_vector_type(4)));

static __device__ __forceinline__ unsigned short f2bf(float f) {
    __hip_bfloat16 h = __float2bfloat16(f);   // RTNE
    return *(unsigned short*)&h;
}
static __device__ __forceinline__ float bf2f(unsigned short u) {
    u32 x = (u32)u << 16;                     // exact widen
    return *(float*)&x;
}

// Async global->LDS, 16B per lane.
typedef const __attribute__((address_space(1))) unsigned int ga_u32;
typedef __attribute__((address_space(3))) unsigned int la_u32;
static __device__ __forceinline__ void gl_lds16(const unsigned short* g,
                                                unsigned short* l_) {
    __builtin_amdgcn_global_load_lds((ga_u32*)g, (la_u32*)l_, 16, 0, 0);
}

#define DRAIN_BAR() asm volatile("s_waitcnt vmcnt(0)\ns_barrier" ::: "memory")

// Fragment tiling: pos(n,k) = ((n>>4)*8 + (k>>5))*512 + (((k>>3)&3)*16 + (n&15))*8 + (k&7).

// ---------------------------------------------------------------------------
// FUSED: LIF(x) + fragment layout (transposed ownership).
__global__ __launch_bounds__(256) void lif_x_frag(const float* __restrict__ X,
                                                  unsigned short* __restrict__ ST) {
    int n = blockIdx.x * 256 + threadIdx.x;
    int c0 = blockIdx.y * 8;
    int k32 = c0 >> 5, quad = (c0 >> 3) & 3;
    size_t base = (size_t)c0 * N_ + n;
    size_t pos = ((size_t)((n >> 4) * 8 + k32)) * 512 +
                 (size_t)((quad * 16 + (n & 15)) * 8);
    float v[8];
#pragma unroll
    for (int j = 0; j < 8; j++) v[j] = 0.f;
#pragma unroll
    for (int t = 0; t < T_; t++) {
        bf16x8 bs;
#pragma unroll
        for (int j = 0; j < 8; j++) {
            float xt = X[(size_t)t * CN_ + base + (size_t)j * N_];
            float vv = v[j] + (xt - v[j]) / 2.0f;
            int s = (vv - 1.0f >= 0.f) ? 1 : 0;
            bs[j] = s ? (short)0x3F80 : (short)0;
            v[j] = s ? 0.f : vv;
        }
        *(bf16x8*)&ST[(size_t)t * CN_ + pos] = bs;
    }
}

// ---------------------------------------------------------------------------
// Branch-indexed LIF: br 0 -> u8 spikes (q), br 1/2 -> bitpacked (k, v).
struct LArgs {
    const float* F[3];
    unsigned char* sq;
    u64* kbp;
    u64* vbp;
};
__global__ __launch_bounds__(256) void lif3(LArgs a) {
    int br = blockIdx.y;
    int idx = blockIdx.x * 256 + threadIdx.x;
    const float* X = a.F[br];
    int lane = threadIdx.x & 63;
    u64* BP = (br == 1) ? a.kbp : a.vbp;
    float v = 0.f;
#pragma unroll
    for (int t = 0; t < T_; t++) {
        float xt = X[(size_t)t * CN_ + idx];
        v = v + (xt - v) / 2.0f;
        int s = (v - 1.0f >= 0.f) ? 1 : 0;
        if (br == 0) {
            a.sq[(size_t)t * CN_ + idx] = (unsigned char)s;
        } else {
            u64 mask = __ballot(s);
            if (lane == 0) BP[((size_t)t * CN_ + idx) >> 6] = mask;
        }
        if (s) v = 0.f;
    }
}

// ---------------------------------------------------------------------------
// Exact 3-way bf16 split of the eight 256x256 weights -> A-fragment layout.
struct WPtrs { const float* w[8]; };
__global__ __launch_bounds__(256) void split_w(WPtrs p, unsigned short* __restrict__ out) {
    int mat = blockIdx.y;
    int idx = blockIdx.x * 256 + threadIdx.x;   // = m*256 + k
    int m = idx >> 8, k = idx & 255;
    float w = p.w[mat][idx];
    unsigned short h1 = f2bf(w);
    float f1 = bf2f(h1);
    unsigned short h2 = f2bf(w - f1);
    unsigned short h3 = f2bf(w - f1 - bf2f(h2));   // exact: 8+8+8 bits
    int lane = ((k >> 3) & 3) * 16 + (m & 15);
    size_t pos = ((size_t)(((m >> 4) * 8 + (k >> 5)) * 64 + lane)) * 8 + (k & 7);
    size_t base = (size_t)mat * 3 * 65536;
    out[base + pos] = h1;
    out[base + 65536 + pos] = h2;
    out[base + 2 * 65536 + pos] = h3;
}

// ---------------------------------------------------------------------------
// Fused dw+BN+pad+split (8 output rows per block).
static __device__ __forceinline__ void dw_body(const float* __restrict__ Yt,
                                               const float* __restrict__ dw,
                                               const float* __restrict__ bnp,
                                               unsigned short* __restrict__ Bh,
                                               unsigned short* __restrict__ Bl,
                                               int y0, int cg, int tid) {
    int c0 = cg * 8;
    __shared__ float L[8][10][68];
    __shared__ float invs[8], bs_[8], ms_[8], pads_[8];

    if (tid < 8) {
        int c = c0 + tid;
        float w = bnp[c], b = bnp[256 + c], m = bnp[512 + c], var = bnp[768 + c];
        float sq = sqrtf(var + EPSB);
        invs[tid] = w / sq;
        bs_[tid] = b;
        ms_[tid] = m;
        pads_[tid] = b - (m * w) / sq;
    }
    __syncthreads();

    for (int i = tid; i < 8 * 10 * 66; i += 256) {
        int c = i / 660;
        int rem = i - c * 660;
        int row = rem / 66, col = rem - row * 66;
        int gy = y0 - 1 + row, gx = col - 1;
        float val;
        if (gy < 0 || gy > 63 || gx < 0 || gx > 63) val = pads_[c];
        else val = (Yt[(size_t)(c0 + c) * N_ + gy * 64 + gx] - ms_[c]) * invs[c] + bs_[c];
        L[c][row][col] = val;
    }
    __syncthreads();

    int x = tid & 63, ry = tid >> 6;
#pragma unroll
    for (int h = 0; h < 2; h++) {
        int r = ry + 4 * h;
        int n = (y0 + r) * 64 + x;

        bf16x8 hi, lo;
#pragma unroll
        for (int j = 0; j < 8; j++) {
            const float* dwc = dw + (c0 + j) * 9;
            float a = 0.f;
#pragma unroll
            for (int dy = 0; dy < 3; dy++)
#pragma unroll
                for (int dx = 0; dx < 3; dx++)
                    a += dwc[dy * 3 + dx] * L[j][r + dy][x + dx];
            unsigned short hh = f2bf(a);
            hi[j] = (short)hh;
            lo[j] = (short)f2bf(a - bf2f(hh));
        }
        size_t pos = ((size_t)((n >> 4) * 8 + (cg >> 2))) * 512 +
                     (size_t)(((cg & 3) * 16 + (n & 15)) * 8);
        *(bf16x8*)&Bh[pos] = hi;
        *(bf16x8*)&Bl[pos] = lo;
    }
}

// Single-branch version (p chain).
__global__ __launch_bounds__(256) void dw_bn_split(const float* __restrict__ Yin,
                                                   const float* __restrict__ dw,
                                                   const float* __restrict__ bnp,
                                                   unsigned short* __restrict__ BhT,
                                                   unsigned short* __restrict__ BlT) {
    int t = blockIdx.z;
    dw_body(Yin + (size_t)t * CN_, dw, bnp,
            BhT + (size_t)t * CN_, BlT + (size_t)t * CN_,
            blockIdx.x * 8, blockIdx.y, threadIdx.x);
}

// Three-branch version (q,k,v in one dispatch). z: br = z>>3, t = z&7.
struct DArgs {
    const float* F[3];
    const float* dw[3];
    const float* bn[3];
    unsigned short* Ph[3];
    unsigned short* Pl[3];
};
__global__ __launch_bounds__(256) void dw3(DArgs a) {
    int br = blockIdx.z >> 3, t = blockIdx.z & 7;
    dw_body(a.F[br] + (size_t)t * CN_, a.dw[br], a.bn[br],
            a.Ph[br] + (size_t)t * CN_, a.Pl[br] + (size_t)t * CN_,
            blockIdx.x * 8, blockIdx.y, threadIdx.x);
}

// ---------------------------------------------------------------------------
// LDS-staged MFMA GEMM cores (128x128 tile, 4 waves 2x2), 2-phase pipelined.
// R3-verified best (907 TF).
static __device__ __forceinline__ void gemm_s_core(const unsigned short* __restrict__ Wsp,
                                                   const unsigned short* __restrict__ Bt,
                                                   float* __restrict__ Yt,
                                                   int bx, int by, int tid) {
    int l = tid & 63, wave = tid >> 6;
    int wm = wave >> 1, wn = wave & 1;
    int lcol = l & 15, quad = l >> 4;

    __shared__ unsigned short As[2][24][512];   // 48KB
    __shared__ unsigned short Bs[2][8][512];    // 16KB   (total 64KB)

    f32x4 acc[4][4];
#pragma unroll
    for (int i = 0; i < 4; i++)
#pragma unroll
        for (int j = 0; j < 4; j++) acc[i][j] = (f32x4){0.f, 0.f, 0.f, 0.f};

    const unsigned short* src[8];
    unsigned short* d0[8];
    unsigned short* d1[8];
#pragma unroll
    for (int i = 0; i < 8; i++) {
        int tau = wave * 8 + i;
        if (tau < 24) {
            int s = tau >> 3, mtg = tau & 7;
            src[i] = &Wsp[(size_t)s * 65536 + ((size_t)((by * 8 + mtg) * 8)) * 512 + l * 8];
            d0[i] = &As[0][tau][0];
            d1[i] = &As[1][tau][0];
        } else {
            int nt = tau - 24;
            src[i] = &Bt[((size_t)((bx * 8 + nt) * 8)) * 512 + l * 8];
            d0[i] = &Bs[0][nt][0];
            d1[i] = &Bs[1][nt][0];
        }
    }

    auto stg0 = [&]() {
#pragma unroll
        for (int i = 0; i < 8; i++) { gl_lds16(src[i], d0[i]); src[i] += 512; }
    };
    auto stg1 = [&]() {
#pragma unroll
        for (int i = 0; i < 8; i++) { gl_lds16(src[i], d1[i]); src[i] += 512; }
    };
    auto compute = [&](const unsigned short (*Asp)[512],
                       const unsigned short (*Bsp)[512]) {
        bf16x8 bfr[4];
#pragma unroll
        for (int nt = 0; nt < 4; nt++)
            bfr[nt] = *(const bf16x8*)&Bsp[wn * 4 + nt][l * 8];
#pragma unroll
        for (int s = 0; s < 3; s++)
#pragma unroll
            for (int mt = 0; mt < 4; mt++) {
                bf16x8 afr = *(const bf16x8*)&Asp[s * 8 + wm * 4 + mt][l * 8];
#pragma unroll
                for (int nt = 0; nt < 4; nt++)
                    acc[mt][nt] = __builtin_amdgcn_mfma_f32_16x16x32_bf16(
                        afr, bfr[nt], acc[mt][nt], 0, 0, 0);
            }
    };

    stg0();
    DRAIN_BAR();

    for (int kk = 0; kk < 8; kk += 2) {
        stg1();
        compute(As[0], Bs[0]);
        DRAIN_BAR();
        if (kk < 6) stg0();
        compute(As[1], Bs[1]);
        DRAIN_BAR();
    }

    int m0 = by * 128, n0 = bx * 128;
#pragma unroll
    for (int mt = 0; mt < 4; mt++)
#pragma unroll
        for (int i = 0; i < 4; i++) {
            int row = m0 + wm * 64 + mt * 16 + quad * 4 + i;
            float* yr = &Yt[(size_t)row * N_ + n0 + wn * 64 + lcol];
#pragma unroll
            for (int nt = 0; nt < 4; nt++) yr[nt * 16] = acc[mt][nt][i];
        }
}

static __device__ __forceinline__ void gemm_f_core(const unsigned short* __restrict__ Wsp,
                                                   const unsigned short* __restrict__ Bht,
                                                   const unsigned short* __restrict__ Blt,
                                                   float* __restrict__ Yt,
                                                   const float* __restrict__ bnp,
                                                   int bx, int by, int tid) {
    int l = tid & 63, wave = tid >> 6;
    int wm = wave >> 1, wn = wave & 1;
    int lcol = l & 15, quad = l >> 4;

    __shared__ unsigned short As[2][24][512];    // 48KB
    __shared__ unsigned short Bhs[2][8][512];    // 16KB
    __shared__ unsigned short Bls[2][8][512];    // 16KB  (total 80KB)

    f32x4 acc[4][4];
#pragma unroll
    for (int i = 0; i < 4; i++)
#pragma unroll
        for (int j = 0; j < 4; j++) acc[i][j] = (f32x4){0.f, 0.f, 0.f, 0.f};

    const unsigned short* src[10];
    unsigned short* d0[10];
    unsigned short* d1[10];
#pragma unroll
    for (int i = 0; i < 10; i++) {
        int tau = wave * 10 + i;
        if (tau < 24) {
            int s = tau >> 3, mtg = tau & 7;
            src[i] = &Wsp[(size_t)s * 65536 + ((size_t)((by * 8 + mtg) * 8)) * 512 + l * 8];
            d0[i] = &As[0][tau][0];
            d1[i] = &As[1][tau][0];
        } else if (tau < 32) {
            int nt = tau - 24;
            src[i] = &Bht[((size_t)((bx * 8 + nt) * 8)) * 512 + l * 8];
            d0[i] = &Bhs[0][nt][0];
            d1[i] = &Bhs[1][nt][0];
        } else {
            int nt = tau - 32;
            src[i] = &Blt[((size_t)((bx * 8 + nt) * 8)) * 512 + l * 8];
            d0[i] = &Bls[0][nt][0];
            d1[i] = &Bls[1][nt][0];
        }
    }

    auto stg0 = [&]() {
#pragma unroll
        for (int i = 0; i < 10; i++) { gl_lds16(src[i], d0[i]); src[i] += 512; }
    };
    auto stg1 = [&]() {
#pragma unroll
        for (int i = 0; i < 10; i++) { gl_lds16(src[i], d1[i]); src[i] += 512; }
    };
    auto compute = [&](const unsigned short (*Asp)[512],
                       const unsigned short (*Bhp)[512],
                       const unsigned short (*Blp)[512]) {
        bf16x8 bh[4], bl[4];
#pragma unroll
        for (int nt = 0; nt < 4; nt++) {
            bh[nt] = *(const bf16x8*)&Bhp[wn * 4 + nt][l * 8];
            bl[nt] = *(const bf16x8*)&Blp[wn * 4 + nt][l * 8];
        }
#pragma unroll
        for (int s = 0; s < 3; s++)
#pragma unroll
            for (int mt = 0; mt < 4; mt++) {
                bf16x8 afr = *(const bf16x8*)&Asp[s * 8 + wm * 4 + mt][l * 8];
#pragma unroll
                for (int nt = 0; nt < 4; nt++)
                    acc[mt][nt] = __builtin_amdgcn_mfma_f32_16x16x32_bf16(
                        afr, bh[nt], acc[mt][nt], 0, 0, 0);
                if (s < 2) {
#pragma unroll
                    for (int nt = 0; nt < 4; nt++)
                        acc[mt][nt] = __builtin_amdgcn_mfma_f32_16x16x32_bf16(
                            afr, bl[nt], acc[mt][nt], 0, 0, 0);
                }
            }
    };

    stg0();
    DRAIN_BAR();

    for (int kk = 0; kk < 8; kk += 2) {
        stg1();
        compute(As[0], Bhs[0], Bls[0]);
        DRAIN_BAR();
        if (kk < 6) stg0();
        compute(As[1], Bhs[1], Bls[1]);
        DRAIN_BAR();
    }

    int m0 = by * 128, n0 = bx * 128;
#pragma unroll
    for (int mt = 0; mt < 4; mt++)
#pragma unroll
        for (int i = 0; i < 4; i++) {
            int row = m0 + wm * 64 + mt * 16 + quad * 4 + i;
            float i1 = bnp[1024 + row] / sqrtf(bnp[1024 + 768 + row] + EPSB);
            float b1 = bnp[1024 + 256 + row], m1 = bnp[1024 + 512 + row];
            float i2 = bnp[2048 + row] / sqrtf(bnp[2048 + 768 + row] + EPSB);
            float b2 = bnp[2048 + 256 + row], m2 = bnp[2048 + 512 + row];
            float* yr = &Yt[(size_t)row * N_ + n0 + wn * 64 + lcol];
#pragma unroll
            for (int nt = 0; nt < 4; nt++)
                yr[nt * 16] = ((acc[mt][nt][i] - m1) * i1 + b1 - m2) * i2 + b2;
        }
}

// ---------------------------------------------------------------------------
// T1 bijective XCD swizzle: grids are exact multiples of 8; w = (b%8)*(n/8)
// + b/8 gives each XCD one contiguous chunk (= one t-slice for these grids),
// so blocks sharing B tiles co-reside on one XCD's L2. Mapping-only change.

// Single-branch wrappers (p chain), swizzled: n=512, chunk=64.
__global__ __launch_bounds__(256) void gemm_s2(const unsigned short* __restrict__ Wsp,
                                               const unsigned short* __restrict__ ST,
                                               float* __restrict__ Y) {
    int b = blockIdx.x + 32 * (blockIdx.y + 2 * blockIdx.z);
    int w = (b & 7) * 64 + (b >> 3);
    int t = w >> 6, by = (w >> 5) & 1, bx = w & 31;
    gemm_s_core(Wsp, ST + (size_t)t * CN_, Y + (size_t)t * CN_,
                bx, by, threadIdx.x);
}
__global__ __launch_bounds__(256) void gemm_f2(const unsigned short* __restrict__ Wsp,
                                               const unsigned short* __restrict__ BhT,
                                               const unsigned short* __restrict__ BlT,
                                               float* __restrict__ Y,
                                               const float* __restrict__ bnp) {
    int b = blockIdx.x + 32 * (blockIdx.y + 2 * blockIdx.z);
    int w = (b & 7) * 64 + (b >> 3);
    int t = w >> 6, by = (w >> 5) & 1, bx = w & 31;
    gemm_f_core(Wsp, BhT + (size_t)t * CN_, BlT + (size_t)t * CN_,
                Y + (size_t)t * CN_, bnp, bx, by, threadIdx.x);
}

// Three-branch wrappers, swizzled: n=1536, chunk=192 (one t per XCD).
struct GSArgs { const unsigned short* W[3]; const unsigned short* ST; float* F[3]; };
__global__ __launch_bounds__(256) void gemm_s3(GSArgs a) {
    int b = blockIdx.x + 32 * (blockIdx.y + 6 * blockIdx.z);
    int w = (b & 7) * 192 + (b >> 3);
    int t = w / 192, r = w - t * 192;
    int y = r >> 5, bx = r & 31;
    int br = y >> 1, byl = y & 1;
    gemm_s_core(a.W[br], a.ST + (size_t)t * CN_, a.F[br] + (size_t)t * CN_,
                bx, byl, threadIdx.x);
}
struct GFArgs {
    const unsigned short* W[3];
    const unsigned short* Ph[3];
    const unsigned short* Pl[3];
    float* F[3];
    const float* bn[3];
};
__global__ __launch_bounds__(256) void gemm_f3(GFArgs a) {
    int b = blockIdx.x + 32 * (blockIdx.y + 6 * blockIdx.z);
    int w = (b & 7) * 192 + (b >> 3);
    int t = w / 192, r = w - t * 192;
    int y = r >> 5, bx = r & 31;
    int br = y >> 1, byl = y & 1;
    gemm_f_core(a.W[br], a.Ph[br] + (size_t)t * CN_, a.Pl[br] + (size_t)t * CN_,
                a.F[br] + (size_t)t * CN_, a.bn[br], bx, byl, threadIdx.x);
}

// ---------------------------------------------------------------------------
// Bitpacked kv, quadrant re-grid (verified bit-exact in R7 mega):
// block = 256 threads computes one d-quadrant (8 d x 32 e) of one (t,h);
// grid 256 blocks (vs 64x1024) -> 4x the resident blocks. Exact popcounts.
__global__ __launch_bounds__(256) void attn_kv_bp(const u64* __restrict__ Kbp,
                                                  const u64* __restrict__ Vbp,
                                                  float* __restrict__ kvbuf) {
    int th = blockIdx.x >> 2, q = blockIdx.x & 3;
    int t = th >> 3, h = th & 7;
    const u64* kb = Kbp + ((size_t)t * C_ + h * 32) * 64;
    const u64* vb = Vbp + ((size_t)t * C_ + h * 32) * 64;
    __shared__ u64 ks[8][65];
    __shared__ u64 vs[32][65];
    int tid = threadIdx.x;
    for (int i = tid; i < 512; i += 256) {
        int r = i >> 6, w = i & 63;
        ks[r][w] = kb[(q * 8 + r) * 64 + w];
    }
    for (int i = tid; i < 2048; i += 256) {
        int r = i >> 6, w = i & 63;
        vs[r][w] = vb[r * 64 + w];
    }
    __syncthreads();
    int dq = tid >> 5, e = tid & 31;
    int cnt = 0;
#pragma unroll
    for (int w = 0; w < 64; w++)
        cnt += __popcll(ks[dq][w] & vs[e][w]);
    kvbuf[(size_t)th * 1024 + (q * 8 + dq) * 32 + e] = (float)cnt;
}

// ---------------------------------------------------------------------------
// FUSED: o = scale * q.kv  +  LIF(o)  +  fragment layout for the p-GEMM.
// (R6 v2 partition: 32 n x 8 e-groups, 1024 blocks = 4/CU.)
__global__ __launch_bounds__(256) void attn_olif(const unsigned char* __restrict__ q,
                                                 const float* __restrict__ kvbuf,
                                                 unsigned short* __restrict__ ST) {
    int h = blockIdx.y;
    int nb = blockIdx.x * 32;
    int tid = threadIdx.x;
    int nj = tid & 31, g = tid >> 5;      // 8 e-groups of 4
    int n = nb + nj;
    int e0 = g * 4;
    __shared__ float kvs[1024];
    const float scale = 0.17677669529663687f;
    float v[4];
#pragma unroll
    for (int e = 0; e < 4; e++) v[e] = 0.f;
    size_t pos = ((size_t)((n >> 4) * 8 + h)) * 512 +
                 (size_t)(((g >> 1) * 16 + (n & 15)) * 8) + (size_t)(4 * (g & 1));
#pragma unroll
    for (int t = 0; t < T_; t++) {
        for (int i = tid; i < 1024; i += 256)
            kvs[i] = kvbuf[(size_t)(t * 8 + h) * 1024 + i];
        __syncthreads();
        float acc[4];
#pragma unroll
        for (int e = 0; e < 4; e++) acc[e] = 0.f;
        const unsigned char* qb = q + (size_t)t * CN_ + (size_t)(h * 32) * N_ + n;
#pragma unroll 4
        for (int d = 0; d < 32; d++) {
            float qd = (float)qb[(size_t)d * N_];
#pragma unroll
            for (int e = 0; e < 4; e++)
                acc[e] += qd * kvs[d * 32 + e0 + e];
        }
        bf16x4 w;
#pragma unroll
        for (int e = 0; e < 4; e++) {
            float o = acc[e] * scale;
            v[e] = v[e] + (o - v[e]) / 2.0f;
            int s = (v[e] - 1.0f >= 0.f) ? 1 : 0;
            w[e] = s ? (short)0x3F80 : (short)0;
            if (s) v[e] = 0.f;
        }
        *(bf16x4*)&ST[(size_t)t * CN_ + pos] = w;
        __syncthreads();
    }
}

// ---------------------------------------------------------------------------
extern "C" void kernel_launch(void* const* d_in, const int* in_sizes, int n_in,
                              void* d_out, int out_size, void* d_ws, size_t ws_size,
                              hipStream_t stream) {
    const float* x = (const float*)d_in[0];
    const float* q_w1 = (const float*)d_in[1];
    const float* q_dw = (const float*)d_in[2];
    const float* q_pw = (const float*)d_in[3];
    const float* q_bn = (const float*)d_in[4];
    const float* k_w1 = (const float*)d_in[5];
    const float* k_dw = (const float*)d_in[6];
    const float* k_pw = (const float*)d_in[7];
    const float* k_bn = (const float*)d_in[8];
    const float* v_w1 = (const float*)d_in[9];
    const float* v_dw = (const float*)d_in[10];
    const float* v_pw = (const float*)d_in[11];
    const float* v_bn = (const float*)d_in[12];
    const float* p_w1 = (const float*)d_in[13];
    const float* p_dw = (const float*)d_in[14];
    const float* p_pw = (const float*)d_in[15];
    const float* p_bn = (const float*)d_in[16];

    const size_t SZ = (size_t)T_ * CN_;   // 8,388,608 elements
    float* out = (float*)d_out;
    float* F0 = (float*)d_ws;
    float* F1 = F0 + SZ;
    float* F2 = F1 + SZ;
    float* P0 = F2 + SZ;
    float* P1 = P0 + SZ;
    float* P2 = P1 + SZ;
    float* bufKV = P2 + SZ;               // 65,536 floats
    unsigned char* xs = (unsigned char*)(bufKV + 65536);   // (unused spare)
    unsigned char* sq = xs + SZ;
    u64* kbp = (u64*)(sq + SZ);
    u64* vbp = kbp + (SZ >> 6);
    unsigned short* wspA = (unsigned short*)(vbp + (SZ >> 6));
    unsigned short* ST = wspA + 8 * 3 * 65536;

    unsigned short* P0h = (unsigned short*)P0; unsigned short* P0l = P0h + SZ;
    unsigned short* P1h = (unsigned short*)P1; unsigned short* P1l = P1h + SZ;
    unsigned short* P2h = (unsigned short*)P2; unsigned short* P2l = P2h + SZ;

    WPtrs wp;
    wp.w[0] = q_w1; wp.w[1] = q_pw; wp.w[2] = k_w1; wp.w[3] = k_pw;
    wp.w[4] = v_w1; wp.w[5] = v_pw; wp.w[6] = p_w1; wp.w[7] = p_pw;
    split_w<<<dim3(256, 8), dim3(256), 0, stream>>>(wp, wspA);
    const size_t WS3 = 3 * 65536;

    // x -> LIF -> spike fragments
    lif_x_frag<<<dim3(N_ / 256, C_ / 8), dim3(256), 0, stream>>>(x, ST);

    // q,k,v first GEMMs (XCD-swizzled)
    GSArgs gs;
    gs.W[0] = wspA + 0 * WS3; gs.W[1] = wspA + 2 * WS3; gs.W[2] = wspA + 4 * WS3;
    gs.ST = ST; gs.F[0] = F0; gs.F[1] = F1; gs.F[2] = F2;
    gemm_s3<<<dim3(N_ / 128, 6, T_), dim3(256), 0, stream>>>(gs);

    // q,k,v dw+BN+split
    DArgs da;
    da.F[0] = F0; da.F[1] = F1; da.F[2] = F2;
    da.dw[0] = q_dw; da.dw[1] = k_dw; da.dw[2] = v_dw;
    da.bn[0] = q_bn; da.bn[1] = k_bn; da.bn[2] = v_bn;
    da.Ph[0] = P0h; da.Ph[1] = P1h; da.Ph[2] = P2h;
    da.Pl[0] = P0l; da.Pl[1] = P1l; da.Pl[2] = P2l;
    dw3<<<dim3(8, 32, 3 * T_), dim3(256), 0, stream>>>(da);

    // q,k,v second GEMMs (XCD-swizzled)
    GFArgs gf;
    gf.W[0] = wspA + 1 * WS3; gf.W[1] = wspA + 3 * WS3; gf.W[2] = wspA + 5 * WS3;
    gf.Ph[0] = P0h; gf.Ph[1] = P1h; gf.Ph[2] = P2h;
    gf.Pl[0] = P0l; gf.Pl[1] = P1l; gf.Pl[2] = P2l;
    gf.F[0] = F0; gf.F[1] = F1; gf.F[2] = F2;
    gf.bn[0] = q_bn; gf.bn[1] = k_bn; gf.bn[2] = v_bn;
    gemm_f3<<<dim3(N_ / 128, 6, T_), dim3(256), 0, stream>>>(gf);

    // q,k,v LIFs
    LArgs la;
    la.F[0] = F0; la.F[1] = F1; la.F[2] = F2;
    la.sq = sq; la.kbp = kbp; la.vbp = vbp;
    lif3<<<dim3(CN_ / 256, 3), dim3(256), 0, stream>>>(la);

    // attention: quadrant kv (256 blocks), fused o+LIF+fragments
    attn_kv_bp<<<dim3(256), dim3(256), 0, stream>>>(kbp, vbp, bufKV);
    attn_olif<<<dim3(N_ / 32, 8), dim3(256), 0, stream>>>(sq, bufKV, ST);

    // p branch (XCD-swizzled GEMMs)
    gemm_s2<<<dim3(N_ / 128, C_ / 128, T_), dim3(256), 0, stream>>>(wspA + 6 * WS3, ST, out);
    dw_bn_split<<<dim3(8, 32, T_), dim3(256), 0, stream>>>(out, p_dw, p_bn, P0h, P0l);
    gemm_f2<<<dim3(N_ / 128, C_ / 128, T_), dim3(256), 0, stream>>>(wspA + 7 * WS3, P0h, P0l, out, p_bn);
}

// Round 9
// 407.107 us; speedup vs baseline: 2.9630x; 1.0135x over previous
//
#include <hip/hip_runtime.h>
#include <hip/hip_bf16.h>
#include <math.h>

// Problem constants: B(=T)=8, C=256, H=W=64, N=4096, heads=8, d=32.
#define T_ 8
#define C_ 256
#define N_ 4096          // H*W
#define CN_ (C_ * N_)    // 1048576 elements per timestep
#define EPSB 1e-5f

typedef unsigned long long u64;
typedef unsigned int u32;
typedef short bf16x8 __attribute__((ext_vector_type(8)));
typedef short bf16x4 __attribute__((ext_vector_type(4)));
typedef float f32x4 __attribute__((ext_vector_type(4)));

static __device__ __forceinline__ unsigned short f2bf(float f) {
    __hip_bfloat16 h = __float2bfloat16(f);   // RTNE
    return *(unsigned short*)&h;
}
static __device__ __forceinline__ float bf2f(unsigned short u) {
    u32 x = (u32)u << 16;                     // exact widen
    return *(float*)&x;
}

// Async global->LDS, 16B per lane.
typedef const __attribute__((address_space(1))) unsigned int ga_u32;
typedef __attribute__((address_space(3))) unsigned int la_u32;
static __device__ __forceinline__ void gl_lds16(const unsigned short* g,
                                                unsigned short* l_) {
    __builtin_amdgcn_global_load_lds((ga_u32*)g, (la_u32*)l_, 16, 0, 0);
}

#define DRAIN_BAR() asm volatile("s_waitcnt vmcnt(0)\ns_barrier" ::: "memory")

// Fragment tiling: pos(n,k) = ((n>>4)*8 + (k>>5))*512 + (((k>>3)&3)*16 + (n&15))*8 + (k&7).

// ---------------------------------------------------------------------------
// FUSED: LIF(x) + fragment layout (transposed ownership).
__global__ __launch_bounds__(256) void lif_x_frag(const float* __restrict__ X,
                                                  unsigned short* __restrict__ ST) {
    int n = blockIdx.x * 256 + threadIdx.x;
    int c0 = blockIdx.y * 8;
    int k32 = c0 >> 5, quad = (c0 >> 3) & 3;
    size_t base = (size_t)c0 * N_ + n;
    size_t pos = ((size_t)((n >> 4) * 8 + k32)) * 512 +
                 (size_t)((quad * 16 + (n & 15)) * 8);
    float v[8];
#pragma unroll
    for (int j = 0; j < 8; j++) v[j] = 0.f;
#pragma unroll
    for (int t = 0; t < T_; t++) {
        bf16x8 bs;
#pragma unroll
        for (int j = 0; j < 8; j++) {
            float xt = X[(size_t)t * CN_ + base + (size_t)j * N_];
            float vv = v[j] + (xt - v[j]) / 2.0f;
            int s = (vv - 1.0f >= 0.f) ? 1 : 0;
            bs[j] = s ? (short)0x3F80 : (short)0;
            v[j] = s ? 0.f : vv;
        }
        *(bf16x8*)&ST[(size_t)t * CN_ + pos] = bs;
    }
}

// ---------------------------------------------------------------------------
// Branch-indexed LIF: br 0 -> u8 spikes (q), br 1/2 -> bitpacked (k, v).
struct LArgs {
    const float* F[3];
    unsigned char* sq;
    u64* kbp;
    u64* vbp;
};
__global__ __launch_bounds__(256) void lif3(LArgs a) {
    int br = blockIdx.y;
    int idx = blockIdx.x * 256 + threadIdx.x;
    const float* X = a.F[br];
    int lane = threadIdx.x & 63;
    u64* BP = (br == 1) ? a.kbp : a.vbp;
    float v = 0.f;
#pragma unroll
    for (int t = 0; t < T_; t++) {
        float xt = X[(size_t)t * CN_ + idx];
        v = v + (xt - v) / 2.0f;
        int s = (v - 1.0f >= 0.f) ? 1 : 0;
        if (br == 0) {
            a.sq[(size_t)t * CN_ + idx] = (unsigned char)s;
        } else {
            u64 mask = __ballot(s);
            if (lane == 0) BP[((size_t)t * CN_ + idx) >> 6] = mask;
        }
        if (s) v = 0.f;
    }
}

// ---------------------------------------------------------------------------
// Exact 3-way bf16 split of the eight 256x256 weights -> A-fragment layout.
struct WPtrs { const float* w[8]; };
__global__ __launch_bounds__(256) void split_w(WPtrs p, unsigned short* __restrict__ out) {
    int mat = blockIdx.y;
    int idx = blockIdx.x * 256 + threadIdx.x;   // = m*256 + k
    int m = idx >> 8, k = idx & 255;
    float w = p.w[mat][idx];
    unsigned short h1 = f2bf(w);
    float f1 = bf2f(h1);
    unsigned short h2 = f2bf(w - f1);
    unsigned short h3 = f2bf(w - f1 - bf2f(h2));   // exact: 8+8+8 bits
    int lane = ((k >> 3) & 3) * 16 + (m & 15);
    size_t pos = ((size_t)(((m >> 4) * 8 + (k >> 5)) * 64 + lane)) * 8 + (k & 7);
    size_t base = (size_t)mat * 3 * 65536;
    out[base + pos] = h1;
    out[base + 65536 + pos] = h2;
    out[base + 2 * 65536 + pos] = h3;
}

// ---------------------------------------------------------------------------
// Fused dw+BN+pad+split (8 output rows per block).
static __device__ __forceinline__ void dw_body(const float* __restrict__ Yt,
                                               const float* __restrict__ dw,
                                               const float* __restrict__ bnp,
                                               unsigned short* __restrict__ Bh,
                                               unsigned short* __restrict__ Bl,
                                               int y0, int cg, int tid) {
    int c0 = cg * 8;
    __shared__ float L[8][10][68];
    __shared__ float invs[8], bs_[8], ms_[8], pads_[8];

    if (tid < 8) {
        int c = c0 + tid;
        float w = bnp[c], b = bnp[256 + c], m = bnp[512 + c], var = bnp[768 + c];
        float sq = sqrtf(var + EPSB);
        invs[tid] = w / sq;
        bs_[tid] = b;
        ms_[tid] = m;
        pads_[tid] = b - (m * w) / sq;
    }
    __syncthreads();

    for (int i = tid; i < 8 * 10 * 66; i += 256) {
        int c = i / 660;
        int rem = i - c * 660;
        int row = rem / 66, col = rem - row * 66;
        int gy = y0 - 1 + row, gx = col - 1;
        float val;
        if (gy < 0 || gy > 63 || gx < 0 || gx > 63) val = pads_[c];
        else val = (Yt[(size_t)(c0 + c) * N_ + gy * 64 + gx] - ms_[c]) * invs[c] + bs_[c];
        L[c][row][col] = val;
    }
    __syncthreads();

    int x = tid & 63, ry = tid >> 6;
#pragma unroll
    for (int h = 0; h < 2; h++) {
        int r = ry + 4 * h;
        int n = (y0 + r) * 64 + x;

        bf16x8 hi, lo;
#pragma unroll
        for (int j = 0; j < 8; j++) {
            const float* dwc = dw + (c0 + j) * 9;
            float a = 0.f;
#pragma unroll
            for (int dy = 0; dy < 3; dy++)
#pragma unroll
                for (int dx = 0; dx < 3; dx++)
                    a += dwc[dy * 3 + dx] * L[j][r + dy][x + dx];
            unsigned short hh = f2bf(a);
            hi[j] = (short)hh;
            lo[j] = (short)f2bf(a - bf2f(hh));
        }
        size_t pos = ((size_t)((n >> 4) * 8 + (cg >> 2))) * 512 +
                     (size_t)(((cg & 3) * 16 + (n & 15)) * 8);
        *(bf16x8*)&Bh[pos] = hi;
        *(bf16x8*)&Bl[pos] = lo;
    }
}

// Single-branch version (p chain).
__global__ __launch_bounds__(256) void dw_bn_split(const float* __restrict__ Yin,
                                                   const float* __restrict__ dw,
                                                   const float* __restrict__ bnp,
                                                   unsigned short* __restrict__ BhT,
                                                   unsigned short* __restrict__ BlT) {
    int t = blockIdx.z;
    dw_body(Yin + (size_t)t * CN_, dw, bnp,
            BhT + (size_t)t * CN_, BlT + (size_t)t * CN_,
            blockIdx.x * 8, blockIdx.y, threadIdx.x);
}

// Three-branch version (q,k,v in one dispatch). z: br = z>>3, t = z&7.
struct DArgs {
    const float* F[3];
    const float* dw[3];
    const float* bn[3];
    unsigned short* Ph[3];
    unsigned short* Pl[3];
};
__global__ __launch_bounds__(256) void dw3(DArgs a) {
    int br = blockIdx.z >> 3, t = blockIdx.z & 7;
    dw_body(a.F[br] + (size_t)t * CN_, a.dw[br], a.bn[br],
            a.Ph[br] + (size_t)t * CN_, a.Pl[br] + (size_t)t * CN_,
            blockIdx.x * 8, blockIdx.y, threadIdx.x);
}

// ---------------------------------------------------------------------------
// LDS-staged MFMA GEMM cores (128x128 tile, 4 waves 2x2), 2-phase pipelined.
// R3-verified best (907 TF). Default block mapping (R8's XCD swizzle measured
// -25% on f3: stride-32 linearization already co-locates B-sharing blocks
// per XCD; the swizzle only de-aligned the t-slice temporal locality).
static __device__ __forceinline__ void gemm_s_core(const unsigned short* __restrict__ Wsp,
                                                   const unsigned short* __restrict__ Bt,
                                                   float* __restrict__ Yt,
                                                   int bx, int by, int tid) {
    int l = tid & 63, wave = tid >> 6;
    int wm = wave >> 1, wn = wave & 1;
    int lcol = l & 15, quad = l >> 4;

    __shared__ unsigned short As[2][24][512];   // 48KB
    __shared__ unsigned short Bs[2][8][512];    // 16KB   (total 64KB)

    f32x4 acc[4][4];
#pragma unroll
    for (int i = 0; i < 4; i++)
#pragma unroll
        for (int j = 0; j < 4; j++) acc[i][j] = (f32x4){0.f, 0.f, 0.f, 0.f};

    const unsigned short* src[8];
    unsigned short* d0[8];
    unsigned short* d1[8];
#pragma unroll
    for (int i = 0; i < 8; i++) {
        int tau = wave * 8 + i;
        if (tau < 24) {
            int s = tau >> 3, mtg = tau & 7;
            src[i] = &Wsp[(size_t)s * 65536 + ((size_t)((by * 8 + mtg) * 8)) * 512 + l * 8];
            d0[i] = &As[0][tau][0];
            d1[i] = &As[1][tau][0];
        } else {
            int nt = tau - 24;
            src[i] = &Bt[((size_t)((bx * 8 + nt) * 8)) * 512 + l * 8];
            d0[i] = &Bs[0][nt][0];
            d1[i] = &Bs[1][nt][0];
        }
    }

    auto stg0 = [&]() {
#pragma unroll
        for (int i = 0; i < 8; i++) { gl_lds16(src[i], d0[i]); src[i] += 512; }
    };
    auto stg1 = [&]() {
#pragma unroll
        for (int i = 0; i < 8; i++) { gl_lds16(src[i], d1[i]); src[i] += 512; }
    };
    auto compute = [&](const unsigned short (*Asp)[512],
                       const unsigned short (*Bsp)[512]) {
        bf16x8 bfr[4];
#pragma unroll
        for (int nt = 0; nt < 4; nt++)
            bfr[nt] = *(const bf16x8*)&Bsp[wn * 4 + nt][l * 8];
#pragma unroll
        for (int s = 0; s < 3; s++)
#pragma unroll
            for (int mt = 0; mt < 4; mt++) {
                bf16x8 afr = *(const bf16x8*)&Asp[s * 8 + wm * 4 + mt][l * 8];
#pragma unroll
                for (int nt = 0; nt < 4; nt++)
                    acc[mt][nt] = __builtin_amdgcn_mfma_f32_16x16x32_bf16(
                        afr, bfr[nt], acc[mt][nt], 0, 0, 0);
            }
    };

    stg0();
    DRAIN_BAR();

    for (int kk = 0; kk < 8; kk += 2) {
        stg1();
        compute(As[0], Bs[0]);
        DRAIN_BAR();
        if (kk < 6) stg0();
        compute(As[1], Bs[1]);
        DRAIN_BAR();
    }

    int m0 = by * 128, n0 = bx * 128;
#pragma unroll
    for (int mt = 0; mt < 4; mt++)
#pragma unroll
        for (int i = 0; i < 4; i++) {
            int row = m0 + wm * 64 + mt * 16 + quad * 4 + i;
            float* yr = &Yt[(size_t)row * N_ + n0 + wn * 64 + lcol];
#pragma unroll
            for (int nt = 0; nt < 4; nt++) yr[nt * 16] = acc[mt][nt][i];
        }
}

static __device__ __forceinline__ void gemm_f_core(const unsigned short* __restrict__ Wsp,
                                                   const unsigned short* __restrict__ Bht,
                                                   const unsigned short* __restrict__ Blt,
                                                   float* __restrict__ Yt,
                                                   const float* __restrict__ bnp,
                                                   int bx, int by, int tid) {
    int l = tid & 63, wave = tid >> 6;
    int wm = wave >> 1, wn = wave & 1;
    int lcol = l & 15, quad = l >> 4;

    __shared__ unsigned short As[2][24][512];    // 48KB
    __shared__ unsigned short Bhs[2][8][512];    // 16KB
    __shared__ unsigned short Bls[2][8][512];    // 16KB  (total 80KB)

    f32x4 acc[4][4];
#pragma unroll
    for (int i = 0; i < 4; i++)
#pragma unroll
        for (int j = 0; j < 4; j++) acc[i][j] = (f32x4){0.f, 0.f, 0.f, 0.f};

    const unsigned short* src[10];
    unsigned short* d0[10];
    unsigned short* d1[10];
#pragma unroll
    for (int i = 0; i < 10; i++) {
        int tau = wave * 10 + i;
        if (tau < 24) {
            int s = tau >> 3, mtg = tau & 7;
            src[i] = &Wsp[(size_t)s * 65536 + ((size_t)((by * 8 + mtg) * 8)) * 512 + l * 8];
            d0[i] = &As[0][tau][0];
            d1[i] = &As[1][tau][0];
        } else if (tau < 32) {
            int nt = tau - 24;
            src[i] = &Bht[((size_t)((bx * 8 + nt) * 8)) * 512 + l * 8];
            d0[i] = &Bhs[0][nt][0];
            d1[i] = &Bhs[1][nt][0];
        } else {
            int nt = tau - 32;
            src[i] = &Blt[((size_t)((bx * 8 + nt) * 8)) * 512 + l * 8];
            d0[i] = &Bls[0][nt][0];
            d1[i] = &Bls[1][nt][0];
        }
    }

    auto stg0 = [&]() {
#pragma unroll
        for (int i = 0; i < 10; i++) { gl_lds16(src[i], d0[i]); src[i] += 512; }
    };
    auto stg1 = [&]() {
#pragma unroll
        for (int i = 0; i < 10; i++) { gl_lds16(src[i], d1[i]); src[i] += 512; }
    };
    auto compute = [&](const unsigned short (*Asp)[512],
                       const unsigned short (*Bhp)[512],
                       const unsigned short (*Blp)[512]) {
        bf16x8 bh[4], bl[4];
#pragma unroll
        for (int nt = 0; nt < 4; nt++) {
            bh[nt] = *(const bf16x8*)&Bhp[wn * 4 + nt][l * 8];
            bl[nt] = *(const bf16x8*)&Blp[wn * 4 + nt][l * 8];
        }
#pragma unroll
        for (int s = 0; s < 3; s++)
#pragma unroll
            for (int mt = 0; mt < 4; mt++) {
                bf16x8 afr = *(const bf16x8*)&Asp[s * 8 + wm * 4 + mt][l * 8];
#pragma unroll
                for (int nt = 0; nt < 4; nt++)
                    acc[mt][nt] = __builtin_amdgcn_mfma_f32_16x16x32_bf16(
                        afr, bh[nt], acc[mt][nt], 0, 0, 0);
                if (s < 2) {
#pragma unroll
                    for (int nt = 0; nt < 4; nt++)
                        acc[mt][nt] = __builtin_amdgcn_mfma_f32_16x16x32_bf16(
                            afr, bl[nt], acc[mt][nt], 0, 0, 0);
                }
            }
    };

    stg0();
    DRAIN_BAR();

    for (int kk = 0; kk < 8; kk += 2) {
        stg1();
        compute(As[0], Bhs[0], Bls[0]);
        DRAIN_BAR();
        if (kk < 6) stg0();
        compute(As[1], Bhs[1], Bls[1]);
        DRAIN_BAR();
    }

    int m0 = by * 128, n0 = bx * 128;
#pragma unroll
    for (int mt = 0; mt < 4; mt++)
#pragma unroll
        for (int i = 0; i < 4; i++) {
            int row = m0 + wm * 64 + mt * 16 + quad * 4 + i;
            float i1 = bnp[1024 + row] / sqrtf(bnp[1024 + 768 + row] + EPSB);
            float b1 = bnp[1024 + 256 + row], m1 = bnp[1024 + 512 + row];
            float i2 = bnp[2048 + row] / sqrtf(bnp[2048 + 768 + row] + EPSB);
            float b2 = bnp[2048 + 256 + row], m2 = bnp[2048 + 512 + row];
            float* yr = &Yt[(size_t)row * N_ + n0 + wn * 64 + lcol];
#pragma unroll
            for (int nt = 0; nt < 4; nt++)
                yr[nt * 16] = ((acc[mt][nt][i] - m1) * i1 + b1 - m2) * i2 + b2;
        }
}

// Single-branch wrappers (p chain).
__global__ __launch_bounds__(256) void gemm_s2(const unsigned short* __restrict__ Wsp,
                                               const unsigned short* __restrict__ ST,
                                               float* __restrict__ Y) {
    int t = blockIdx.z;
    gemm_s_core(Wsp, ST + (size_t)t * CN_, Y + (size_t)t * CN_,
                blockIdx.x, blockIdx.y, threadIdx.x);
}
__global__ __launch_bounds__(256) void gemm_f2(const unsigned short* __restrict__ Wsp,
                                               const unsigned short* __restrict__ BhT,
                                               const unsigned short* __restrict__ BlT,
                                               float* __restrict__ Y,
                                               const float* __restrict__ bnp) {
    int t = blockIdx.z;
    gemm_f_core(Wsp, BhT + (size_t)t * CN_, BlT + (size_t)t * CN_,
                Y + (size_t)t * CN_, bnp, blockIdx.x, blockIdx.y, threadIdx.x);
}

// Three-branch mega-dispatch wrappers. by: br = by>>1, m-half = by&1.
struct GSArgs { const unsigned short* W[3]; const unsigned short* ST; float* F[3]; };
__global__ __launch_bounds__(256) void gemm_s3(GSArgs a) {
    int t = blockIdx.z;
    int br = blockIdx.y >> 1, byl = blockIdx.y & 1;
    gemm_s_core(a.W[br], a.ST + (size_t)t * CN_, a.F[br] + (size_t)t * CN_,
                blockIdx.x, byl, threadIdx.x);
}
struct GFArgs {
    const unsigned short* W[3];
    const unsigned short* Ph[3];
    const unsigned short* Pl[3];
    float* F[3];
    const float* bn[3];
};
__global__ __launch_bounds__(256) void gemm_f3(GFArgs a) {
    int t = blockIdx.z;
    int br = blockIdx.y >> 1, byl = blockIdx.y & 1;
    gemm_f_core(a.W[br], a.Ph[br] + (size_t)t * CN_, a.Pl[br] + (size_t)t * CN_,
                a.F[br] + (size_t)t * CN_, a.bn[br], blockIdx.x, byl, threadIdx.x);
}

// ---------------------------------------------------------------------------
// Bitpacked kv, quadrant re-grid (bit-exact, verified in R7/R8): block = 256
// threads computes one d-quadrant (8 d x 32 e) of one (t,h); 256 blocks.
__global__ __launch_bounds__(256) void attn_kv_bp(const u64* __restrict__ Kbp,
                                                  const u64* __restrict__ Vbp,
                                                  float* __restrict__ kvbuf) {
    int th = blockIdx.x >> 2, q = blockIdx.x & 3;
    int t = th >> 3, h = th & 7;
    const u64* kb = Kbp + ((size_t)t * C_ + h * 32) * 64;
    const u64* vb = Vbp + ((size_t)t * C_ + h * 32) * 64;
    __shared__ u64 ks[8][65];
    __shared__ u64 vs[32][65];
    int tid = threadIdx.x;
    for (int i = tid; i < 512; i += 256) {
        int r = i >> 6, w = i & 63;
        ks[r][w] = kb[(q * 8 + r) * 64 + w];
    }
    for (int i = tid; i < 2048; i += 256) {
        int r = i >> 6, w = i & 63;
        vs[r][w] = vb[r * 64 + w];
    }
    __syncthreads();
    int dq = tid >> 5, e = tid & 31;
    int cnt = 0;
#pragma unroll
    for (int w = 0; w < 64; w++)
        cnt += __popcll(ks[dq][w] & vs[e][w]);
    kvbuf[(size_t)th * 1024 + (q * 8 + dq) * 32 + e] = (float)cnt;
}

// ---------------------------------------------------------------------------
// FUSED: o = scale * q.kv  +  LIF(o)  +  fragment layout for the p-GEMM.
// (R6 v2 partition: 32 n x 8 e-groups, 1024 blocks = 4/CU.)
__global__ __launch_bounds__(256) void attn_olif(const unsigned char* __restrict__ q,
                                                 const float* __restrict__ kvbuf,
                                                 unsigned short* __restrict__ ST) {
    int h = blockIdx.y;
    int nb = blockIdx.x * 32;
    int tid = threadIdx.x;
    int nj = tid & 31, g = tid >> 5;      // 8 e-groups of 4
    int n = nb + nj;
    int e0 = g * 4;
    __shared__ float kvs[1024];
    const float scale = 0.17677669529663687f;
    float v[4];
#pragma unroll
    for (int e = 0; e < 4; e++) v[e] = 0.f;
    size_t pos = ((size_t)((n >> 4) * 8 + h)) * 512 +
                 (size_t)(((g >> 1) * 16 + (n & 15)) * 8) + (size_t)(4 * (g & 1));
#pragma unroll
    for (int t = 0; t < T_; t++) {
        for (int i = tid; i < 1024; i += 256)
            kvs[i] = kvbuf[(size_t)(t * 8 + h) * 1024 + i];
        __syncthreads();
        float acc[4];
#pragma unroll
        for (int e = 0; e < 4; e++) acc[e] = 0.f;
        const unsigned char* qb = q + (size_t)t * CN_ + (size_t)(h * 32) * N_ + n;
#pragma unroll 4
        for (int d = 0; d < 32; d++) {
            float qd = (float)qb[(size_t)d * N_];
#pragma unroll
            for (int e = 0; e < 4; e++)
                acc[e] += qd * kvs[d * 32 + e0 + e];
        }
        bf16x4 w;
#pragma unroll
        for (int e = 0; e < 4; e++) {
            float o = acc[e] * scale;
            v[e] = v[e] + (o - v[e]) / 2.0f;
            int s = (v[e] - 1.0f >= 0.f) ? 1 : 0;
            w[e] = s ? (short)0x3F80 : (short)0;
            if (s) v[e] = 0.f;
        }
        *(bf16x4*)&ST[(size_t)t * CN_ + pos] = w;
        __syncthreads();
    }
}

// ---------------------------------------------------------------------------
extern "C" void kernel_launch(void* const* d_in, const int* in_sizes, int n_in,
                              void* d_out, int out_size, void* d_ws, size_t ws_size,
                              hipStream_t stream) {
    const float* x = (const float*)d_in[0];
    const float* q_w1 = (const float*)d_in[1];
    const float* q_dw = (const float*)d_in[2];
    const float* q_pw = (const float*)d_in[3];
    const float* q_bn = (const float*)d_in[4];
    const float* k_w1 = (const float*)d_in[5];
    const float* k_dw = (const float*)d_in[6];
    const float* k_pw = (const float*)d_in[7];
    const float* k_bn = (const float*)d_in[8];
    const float* v_w1 = (const float*)d_in[9];
    const float* v_dw = (const float*)d_in[10];
    const float* v_pw = (const float*)d_in[11];
    const float* v_bn = (const float*)d_in[12];
    const float* p_w1 = (const float*)d_in[13];
    const float* p_dw = (const float*)d_in[14];
    const float* p_pw = (const float*)d_in[15];
    const float* p_bn = (const float*)d_in[16];

    const size_t SZ = (size_t)T_ * CN_;   // 8,388,608 elements
    float* out = (float*)d_out;
    float* F0 = (float*)d_ws;
    float* F1 = F0 + SZ;
    float* F2 = F1 + SZ;
    float* P0 = F2 + SZ;
    float* P1 = P0 + SZ;
    float* P2 = P1 + SZ;
    float* bufKV = P2 + SZ;               // 65,536 floats
    unsigned char* xs = (unsigned char*)(bufKV + 65536);   // (unused spare)
    unsigned char* sq = xs + SZ;
    u64* kbp = (u64*)(sq + SZ);
    u64* vbp = kbp + (SZ >> 6);
    unsigned short* wspA = (unsigned short*)(vbp + (SZ >> 6));
    unsigned short* ST = wspA + 8 * 3 * 65536;

    unsigned short* P0h = (unsigned short*)P0; unsigned short* P0l = P0h + SZ;
    unsigned short* P1h = (unsigned short*)P1; unsigned short* P1l = P1h + SZ;
    unsigned short* P2h = (unsigned short*)P2; unsigned short* P2l = P2h + SZ;

    WPtrs wp;
    wp.w[0] = q_w1; wp.w[1] = q_pw; wp.w[2] = k_w1; wp.w[3] = k_pw;
    wp.w[4] = v_w1; wp.w[5] = v_pw; wp.w[6] = p_w1; wp.w[7] = p_pw;
    split_w<<<dim3(256, 8), dim3(256), 0, stream>>>(wp, wspA);
    const size_t WS3 = 3 * 65536;

    // x -> LIF -> spike fragments
    lif_x_frag<<<dim3(N_ / 256, C_ / 8), dim3(256), 0, stream>>>(x, ST);

    // q,k,v first GEMMs (default mapping — R3/R6-verified best)
    GSArgs gs;
    gs.W[0] = wspA + 0 * WS3; gs.W[1] = wspA + 2 * WS3; gs.W[2] = wspA + 4 * WS3;
    gs.ST = ST; gs.F[0] = F0; gs.F[1] = F1; gs.F[2] = F2;
    gemm_s3<<<dim3(N_ / 128, 6, T_), dim3(256), 0, stream>>>(gs);

    // q,k,v dw+BN+split
    DArgs da;
    da.F[0] = F0; da.F[1] = F1; da.F[2] = F2;
    da.dw[0] = q_dw; da.dw[1] = k_dw; da.dw[2] = v_dw;
    da.bn[0] = q_bn; da.bn[1] = k_bn; da.bn[2] = v_bn;
    da.Ph[0] = P0h; da.Ph[1] = P1h; da.Ph[2] = P2h;
    da.Pl[0] = P0l; da.Pl[1] = P1l; da.Pl[2] = P2l;
    dw3<<<dim3(8, 32, 3 * T_), dim3(256), 0, stream>>>(da);

    // q,k,v second GEMMs
    GFArgs gf;
    gf.W[0] = wspA + 1 * WS3; gf.W[1] = wspA + 3 * WS3; gf.W[2] = wspA + 5 * WS3;
    gf.Ph[0] = P0h; gf.Ph[1] = P1h; gf.Ph[2] = P2h;
    gf.Pl[0] = P0l; gf.Pl[1] = P1l; gf.Pl[2] = P2l;
    gf.F[0] = F0; gf.F[1] = F1; gf.F[2] = F2;
    gf.bn[0] = q_bn; gf.bn[1] = k_bn; gf.bn[2] = v_bn;
    gemm_f3<<<dim3(N_ / 128, 6, T_), dim3(256), 0, stream>>>(gf);

    // q,k,v LIFs
    LArgs la;
    la.F[0] = F0; la.F[1] = F1; la.F[2] = F2;
    la.sq = sq; la.kbp = kbp; la.vbp = vbp;
    lif3<<<dim3(CN_ / 256, 3), dim3(256), 0, stream>>>(la);

    // attention: quadrant kv (256 blocks), fused o+LIF+fragments
    attn_kv_bp<<<dim3(256), dim3(256), 0, stream>>>(kbp, vbp, bufKV);
    attn_olif<<<dim3(N_ / 32, 8), dim3(256), 0, stream>>>(sq, bufKV, ST);

    // p branch
    gemm_s2<<<dim3(N_ / 128, C_ / 128, T_), dim3(256), 0, stream>>>(wspA + 6 * WS3, ST, out);
    dw_bn_split<<<dim3(8, 32, T_), dim3(256), 0, stream>>>(out, p_dw, p_bn, P0h, P0l);
    gemm_f2<<<dim3(N_ / 128, C_ / 128, T_), dim3(256), 0, stream>>>(wspA + 7 * WS3, P0h, P0l, out, p_bn);
}